// Round 1
// baseline (106.352 us; speedup 1.0000x reference)
//
#include <hip/hip_runtime.h>
#include <cstdint>

#define CHUNKS 16

// Kernel 1: one thread per pred row i, chunk of gt boxes per blockIdx.y.
// Inner loop is wave-uniform in j -> gt box comes in via scalar loads
// (s_load_dwordx4), amortized across all 64 lanes.
__global__ __launch_bounds__(256) void k_pairwise(
    const float4* __restrict__ pred, const float4* __restrict__ gt,
    uint8_t* __restrict__ flags, int N, int M, int Mc)
{
    int i = blockIdx.x * 256 + threadIdx.x;
    int ii = i < N ? i : N - 1;            // clamp read; store is guarded
    float4 b = pred[ii];
    float a1 = (b.z - b.x) * (b.w - b.y);

    int j0 = blockIdx.y * Mc;
    int j1 = j0 + Mc;
    if (j1 > M) j1 = M;

    bool found = false;
    #pragma unroll 4
    for (int j = j0; j < j1; ++j) {
        float4 g = gt[j];                  // uniform address -> s_load
        float ga  = (g.z - g.x) * (g.w - g.y);
        float ix1 = fmaxf(b.x, g.x);
        float iy1 = fmaxf(b.y, g.y);
        float ix2 = fminf(b.z, g.z);
        float iy2 = fminf(b.w, g.w);
        float dx  = fmaxf(ix2 - ix1, 0.0f);
        float dy  = fmaxf(iy2 - iy1, 0.0f);
        float inter = dx * dy;
        float denom = ((a1 + ga) - inter) + 1e-6f;   // union + eps
        bool hit = (inter + inter) >= denom;         // iou >= 0.5
        found = found | hit;                         // SGPR lane-mask s_or
    }
    if (i < N) flags[blockIdx.y * N + i] = found ? (uint8_t)1 : (uint8_t)0;
}

// Kernel 2: OR the chunk flags, BCE term per row, block-reduce, atomicAdd.
__global__ __launch_bounds__(256) void k_loss(
    const float* __restrict__ scores, const uint8_t* __restrict__ flags,
    float* __restrict__ out, int N)
{
    float acc = 0.0f;
    for (int i = blockIdx.x * 256 + threadIdx.x; i < N; i += gridDim.x * 256) {
        int f = 0;
        #pragma unroll
        for (int c = 0; c < CHUNKS; ++c) f |= flags[c * N + i];
        float p  = scores[i];
        float lp = fmaxf(logf(p),     -100.0f);
        float l1 = fmaxf(log1pf(-p),  -100.0f);
        acc += f ? lp : l1;
    }
    // wave reduce (64 lanes)
    for (int o = 32; o > 0; o >>= 1) acc += __shfl_down(acc, o, 64);
    __shared__ float sm[4];
    int lane = threadIdx.x & 63, w = threadIdx.x >> 6;
    if (lane == 0) sm[w] = acc;
    __syncthreads();
    if (threadIdx.x == 0) {
        float s = sm[0] + sm[1] + sm[2] + sm[3];
        atomicAdd(out, -s / (float)N);
    }
}

extern "C" void kernel_launch(void* const* d_in, const int* in_sizes, int n_in,
                              void* d_out, int out_size, void* d_ws, size_t ws_size,
                              hipStream_t stream) {
    const float*  scores = (const float*)d_in[0];
    const float4* pred   = (const float4*)d_in[1];
    const float4* gt     = (const float4*)d_in[2];
    float* out = (float*)d_out;
    uint8_t* flags = (uint8_t*)d_ws;

    int N = in_sizes[0];          // 20000 scores == pred rows
    int M = in_sizes[2] / 4;      // 4000 gt boxes
    int Mc = (M + CHUNKS - 1) / CHUNKS;

    hipMemsetAsync(d_out, 0, out_size * sizeof(float), stream);

    dim3 g1((N + 255) / 256, CHUNKS);
    k_pairwise<<<g1, dim3(256), 0, stream>>>(pred, gt, flags, N, M, Mc);

    k_loss<<<dim3(80), dim3(256), 0, stream>>>(scores, flags, out, N);
}

// Round 2
// 100.881 us; speedup vs baseline: 1.0542x; 1.0542x over previous
//
#include <hip/hip_runtime.h>
#include <cstdint>

#define CHUNKS 25
#define EPS_IOU 1e-6f

// Prep: per-gt area (+eps) precomputed once; also zero the output scalar
// (replaces the memset node; k_loss atomicAdds into it).
__global__ __launch_bounds__(256) void k_prep(
    const float4* __restrict__ gt, float* __restrict__ gae, int M,
    float* __restrict__ out)
{
    int j = blockIdx.x * 256 + threadIdx.x;
    if (j < M) {
        float4 g = gt[j];
        gae[j] = (g.z - g.x) * (g.w - g.y) + EPS_IOU;
    }
    if (blockIdx.x == 0 && threadIdx.x == 0) out[0] = 0.0f;
}

// One thread per pred row, gt chunk per blockIdx.y. j is wave-uniform ->
// gt box + area arrive via scalar loads (s_load_dwordx4 / s_load_dword).
// Test: iou >= 0.5  <=>  2*inter >= union+eps  <=>  3*inter >= a1+ga+eps.
// 12 VALU ops per pair.
__global__ __launch_bounds__(256) void k_pairwise(
    const float4* __restrict__ pred, const float4* __restrict__ gt,
    const float* __restrict__ gae, uint8_t* __restrict__ flags,
    int N, int M, int Mc)
{
    int i = blockIdx.x * 256 + threadIdx.x;
    int ii = i < N ? i : N - 1;            // clamp read; store is guarded
    float4 b = pred[ii];
    float a1 = (b.z - b.x) * (b.w - b.y);

    int j0 = blockIdx.y * Mc;
    int j1 = j0 + Mc;
    if (j1 > M) j1 = M;

    bool found = false;
    #pragma unroll 8
    for (int j = j0; j < j1; ++j) {
        float4 g  = gt[j];                 // uniform -> s_load_dwordx4
        float rhs = a1 + gae[j];           // gae uniform -> s_load_dword
        float dx  = fmaxf(fminf(b.z, g.z) - fmaxf(b.x, g.x), 0.0f);
        float dy  = fmaxf(fminf(b.w, g.w) - fmaxf(b.y, g.y), 0.0f);
        found |= (fmaf(dx * dy, 3.0f, -rhs) >= 0.0f);   // s_or_b64 accumulate
    }
    if (i < N) flags[blockIdx.y * N + i] = found ? (uint8_t)1 : (uint8_t)0;
}

// OR the chunk flags, BCE term per row, block-reduce, atomicAdd.
__global__ __launch_bounds__(256) void k_loss(
    const float* __restrict__ scores, const uint8_t* __restrict__ flags,
    float* __restrict__ out, int N)
{
    float acc = 0.0f;
    for (int i = blockIdx.x * 256 + threadIdx.x; i < N; i += gridDim.x * 256) {
        int f = 0;
        #pragma unroll
        for (int c = 0; c < CHUNKS; ++c) f |= flags[c * N + i];
        float p  = scores[i];
        float lp = fmaxf(logf(p),     -100.0f);
        float l1 = fmaxf(log1pf(-p),  -100.0f);
        acc += f ? lp : l1;
    }
    for (int o = 32; o > 0; o >>= 1) acc += __shfl_down(acc, o, 64);
    __shared__ float sm[4];
    int lane = threadIdx.x & 63, w = threadIdx.x >> 6;
    if (lane == 0) sm[w] = acc;
    __syncthreads();
    if (threadIdx.x == 0) {
        float s = sm[0] + sm[1] + sm[2] + sm[3];
        atomicAdd(out, -s / (float)N);
    }
}

extern "C" void kernel_launch(void* const* d_in, const int* in_sizes, int n_in,
                              void* d_out, int out_size, void* d_ws, size_t ws_size,
                              hipStream_t stream) {
    const float*  scores = (const float*)d_in[0];
    const float4* pred   = (const float4*)d_in[1];
    const float4* gt     = (const float4*)d_in[2];
    float* out = (float*)d_out;

    int N = in_sizes[0];          // 20000 pred rows
    int M = in_sizes[2] / 4;      // 4000 gt boxes
    int Mc = (M + CHUNKS - 1) / CHUNKS;   // 160

    float*   gae   = (float*)d_ws;                       // 16 KB
    uint8_t* flags = (uint8_t*)d_ws + 16384;             // CHUNKS*N bytes

    k_prep<<<dim3((M + 255) / 256), dim3(256), 0, stream>>>(gt, gae, M, out);

    dim3 g1((N + 255) / 256, CHUNKS);
    k_pairwise<<<g1, dim3(256), 0, stream>>>(pred, gt, gae, flags, N, M, Mc);

    k_loss<<<dim3(80), dim3(256), 0, stream>>>(scores, flags, out, N);
}